// Round 3
// baseline (611.681 us; speedup 1.0000x reference)
//
#include <hip/hip_runtime.h>

// GNN NodeEncoder: 2 layers of
//   h = relu(x@Wr + br + mean_in(x[src])@W1 + mean_out(x[dst])@W2)
// Algebra: scatter_mean((x@W)[src],dst) == scatter_mean(x[src],dst)@W -> aggregate
// RAW features, apply weights after as a GEMM.
// Pipeline: CSR build once (graph shared by both layers); per layer:
//   k_gather: per-node wave, float4-row gather (4 rows/instr), means written as
//             split-bf16 (hi+lo) A=[mean_in|mean_out]  [N,128]
//   k_gemm:   MFMA split-bf16 GEMM A@Wcat + x@Wr + br, relu. 3 passes
//             (hh,hl,lh) give ~fp32 precision on matrix cores.

typedef __bf16 bf16x8 __attribute__((ext_vector_type(8)));
typedef float  f32x4  __attribute__((ext_vector_type(4)));

// ---------------- CSR build ----------------
__global__ void k_degree(const int* __restrict__ ei, int E,
                         int* __restrict__ deg_in, int* __restrict__ deg_out) {
    int e = blockIdx.x * blockDim.x + threadIdx.x;
    if (e >= E) return;
    atomicAdd(&deg_in[ei[E + e]], 1);   // dst
    atomicAdd(&deg_out[ei[e]], 1);      // src
}

__global__ void k_chunksum(const int* __restrict__ deg_in, const int* __restrict__ deg_out,
                           int n, int* __restrict__ bsum /* [2][1024] */) {
    __shared__ int sm[256];
    const int* deg = (blockIdx.y == 0) ? deg_in : deg_out;
    int i = blockIdx.x * 256 + threadIdx.x;
    sm[threadIdx.x] = (i < n) ? deg[i] : 0;
    __syncthreads();
    for (int off = 128; off > 0; off >>= 1) {
        if (threadIdx.x < off) sm[threadIdx.x] += sm[threadIdx.x + off];
        __syncthreads();
    }
    if (threadIdx.x == 0) bsum[blockIdx.y * 1024 + blockIdx.x] = sm[0];
}

__global__ void k_scanchunks(int* __restrict__ bsum, int nchunks) {
    __shared__ int sm[1024];
    int* b = bsum + blockIdx.x * 1024;
    int tid = threadIdx.x;
    int v = (tid < nchunks) ? b[tid] : 0;
    sm[tid] = v;
    __syncthreads();
    for (int off = 1; off < 1024; off <<= 1) {
        int t = (tid >= off) ? sm[tid - off] : 0;
        __syncthreads();
        sm[tid] += t;
        __syncthreads();
    }
    if (tid < nchunks) b[tid] = sm[tid] - v;  // exclusive offsets
}

__global__ void k_scatterscan(const int* __restrict__ deg_in, const int* __restrict__ deg_out,
                              int n, const int* __restrict__ bsum,
                              int* __restrict__ rp_in, int* __restrict__ rp_out) {
    __shared__ int sm[256];
    const int* deg = (blockIdx.y == 0) ? deg_in : deg_out;
    int* rp = (blockIdx.y == 0) ? rp_in : rp_out;
    int i = blockIdx.x * 256 + threadIdx.x;
    int tid = threadIdx.x;
    int v = (i < n) ? deg[i] : 0;
    sm[tid] = v;
    __syncthreads();
    for (int off = 1; off < 256; off <<= 1) {
        int t = (tid >= off) ? sm[tid - off] : 0;
        __syncthreads();
        sm[tid] += t;
        __syncthreads();
    }
    int choff = bsum[blockIdx.y * 1024 + blockIdx.x];
    if (i < n) rp[i + 1] = choff + sm[tid];
    if (i == 0) rp[0] = 0;
}

__global__ void k_fill(const int* __restrict__ ei, int E,
                       const int* __restrict__ rp_in, const int* __restrict__ rp_out,
                       int* __restrict__ cur_in, int* __restrict__ cur_out,
                       int* __restrict__ ci_in, int* __restrict__ ci_out) {
    int e = blockIdx.x * blockDim.x + threadIdx.x;
    if (e >= E) return;
    int s = ei[e];
    int d = ei[E + e];
    int p = atomicAdd(&cur_in[d], 1);
    ci_in[rp_in[d] + p] = s;
    int q = atomicAdd(&cur_out[s], 1);
    ci_out[rp_out[s] + q] = d;
}

// ---------------- weight prep: WcatT = [W1;W2]^T, WrT = Wr^T, split bf16 ----------------
// WcT: [64 n][128 k] (k<64 from W1, k>=64 from W2); WrT: [64 n][64 k]
__global__ void k_prep(const float* __restrict__ W1, const float* __restrict__ W2,
                       const float* __restrict__ Wr,
                       __bf16* __restrict__ WcT_h, __bf16* __restrict__ WcT_l,
                       __bf16* __restrict__ WrT_h, __bf16* __restrict__ WrT_l) {
    int i = blockIdx.x * 256 + threadIdx.x;  // 12288 total
    if (i < 8192) {
        int nn = i >> 7, k = i & 127;
        float w = (k < 64) ? W1[k * 64 + nn] : W2[(k - 64) * 64 + nn];
        __bf16 h = (__bf16)w;
        WcT_h[i] = h;
        WcT_l[i] = (__bf16)(w - (float)h);
    } else if (i < 12288) {
        int j = i - 8192;
        int nn = j >> 6, k = j & 63;
        float w = Wr[k * 64 + nn];
        __bf16 h = (__bf16)w;
        WrT_h[j] = h;
        WrT_l[j] = (__bf16)(w - (float)h);
    }
}

// ---------------- gather: per-node wave, float4 rows, split-bf16 A out ----------------
// lane = 16*sub + q: sub in 0..3 picks neighbor-within-group, q picks float4 col chunk.
__launch_bounds__(256, 8)
__global__ void k_gather(const float* __restrict__ Hin,
                         const int* __restrict__ rp_in, const int* __restrict__ ci_in,
                         const int* __restrict__ rp_out, const int* __restrict__ ci_out,
                         __bf16* __restrict__ Ah, __bf16* __restrict__ Al, int n) {
    const int lane = threadIdx.x & 63;
    const int wid  = threadIdx.x >> 6;
    const int v = blockIdx.x * 4 + wid;
    if (v >= n) return;
    const int q = lane & 15, sub = lane >> 4;

    #pragma unroll
    for (int dir = 0; dir < 2; ++dir) {
        const int* rp = dir ? rp_out : rp_in;
        const int* ci = dir ? ci_out : ci_in;
        int s = rp[v], e = rp[v + 1];
        float ax = 0.f, ay = 0.f, az = 0.f, aw = 0.f;
        int t = s;
        for (; t + 8 <= e; t += 8) {  // 8 rows per iter, 2 x 1KB gathers in flight
            int u0 = ci[t + sub];          // 16-lane broadcast load, L1-hot
            int u1 = ci[t + 4 + sub];
            float4 f0 = *(const float4*)(Hin + (size_t)u0 * 64 + q * 4);
            float4 f1 = *(const float4*)(Hin + (size_t)u1 * 64 + q * 4);
            ax += f0.x + f1.x; ay += f0.y + f1.y;
            az += f0.z + f1.z; aw += f0.w + f1.w;
        }
        for (; t < e; t += 4) {  // tail, predicated per sub-group
            int r = t + sub;
            if (r < e) {
                int u = ci[r];
                float4 f = *(const float4*)(Hin + (size_t)u * 64 + q * 4);
                ax += f.x; ay += f.y; az += f.z; aw += f.w;
            }
        }
        // reduce across the 4 sub groups (lanes ^16, ^32)
        ax += __shfl_xor(ax, 16, 64); ax += __shfl_xor(ax, 32, 64);
        ay += __shfl_xor(ay, 16, 64); ay += __shfl_xor(ay, 32, 64);
        az += __shfl_xor(az, 16, 64); az += __shfl_xor(az, 32, 64);
        aw += __shfl_xor(aw, 16, 64); aw += __shfl_xor(aw, 32, 64);
        float inv = 1.0f / (float)max(e - s, 1);
        ax *= inv; ay *= inv; az *= inv; aw *= inv;

        if (sub == 0) {  // 16 lanes write the 64-col block as split bf16
            union { __bf16 h[4]; uint2 u2; } ph, pl;
            float m[4] = {ax, ay, az, aw};
            #pragma unroll
            for (int c = 0; c < 4; ++c) {
                __bf16 h = (__bf16)m[c];
                ph.h[c] = h;
                pl.h[c] = (__bf16)(m[c] - (float)h);
            }
            size_t off = (size_t)v * 128 + dir * 64 + q * 4;
            *(uint2*)(Ah + off) = ph.u2;
            *(uint2*)(Al + off) = pl.u2;
        }
    }
}

// ---------------- MFMA GEMM: out = relu(A@Wcat + Hin@Wr + br) ----------------
// block 256 = 4 waves, 64 rows/block (16 rows/wave), full N=64 cols per wave.
// mfma_f32_16x16x32_bf16: A-frag row = lane&15, k = 8*(lane>>4)+j (any consistent
// k-order is fine: same packing for A and B makes the k-permutation cancel).
// C/D: col = lane&15, row = (lane>>4)*4 + reg   [verified layout]
__global__ void k_gemm(const __bf16* __restrict__ Ah, const __bf16* __restrict__ Al,
                       const float* __restrict__ Hin,
                       const __bf16* __restrict__ WcT_h, const __bf16* __restrict__ WcT_l,
                       const __bf16* __restrict__ WrT_h, const __bf16* __restrict__ WrT_l,
                       const float* __restrict__ br, float* __restrict__ Hout, int n) {
    const int lane = threadIdx.x & 63;
    const int wid  = threadIdx.x >> 6;
    const int q = lane & 15, sub = lane >> 4;
    const int rowbase = blockIdx.x * 64 + wid * 16;
    const int arow = min(rowbase + q, n - 1);   // A-operand row for this lane

    f32x4 acc[4];
    #pragma unroll
    for (int nf = 0; nf < 4; ++nf) acc[nf] = (f32x4){0.f, 0.f, 0.f, 0.f};

    // A @ Wcat  (K = 128)
    #pragma unroll
    for (int ks = 0; ks < 4; ++ks) {
        const size_t ao = (size_t)arow * 128 + ks * 32 + sub * 8;
        bf16x8 a_h = *(const bf16x8*)(Ah + ao);
        bf16x8 a_l = *(const bf16x8*)(Al + ao);
        #pragma unroll
        for (int nf = 0; nf < 4; ++nf) {
            const size_t bo = (size_t)(nf * 16 + q) * 128 + ks * 32 + sub * 8;
            bf16x8 b_h = *(const bf16x8*)(WcT_h + bo);
            bf16x8 b_l = *(const bf16x8*)(WcT_l + bo);
            acc[nf] = __builtin_amdgcn_mfma_f32_16x16x32_bf16(a_h, b_h, acc[nf], 0, 0, 0);
            acc[nf] = __builtin_amdgcn_mfma_f32_16x16x32_bf16(a_h, b_l, acc[nf], 0, 0, 0);
            acc[nf] = __builtin_amdgcn_mfma_f32_16x16x32_bf16(a_l, b_h, acc[nf], 0, 0, 0);
        }
    }
    // Hin @ Wr  (K = 64), convert fp32 -> hi/lo in-register
    #pragma unroll
    for (int ks = 0; ks < 2; ++ks) {
        const float* hp = Hin + (size_t)arow * 64 + ks * 32 + sub * 8;
        float4 h0 = *(const float4*)hp;
        float4 h1 = *(const float4*)(hp + 4);
        float hf[8] = {h0.x, h0.y, h0.z, h0.w, h1.x, h1.y, h1.z, h1.w};
        bf16x8 a_h, a_l;
        #pragma unroll
        for (int c = 0; c < 8; ++c) {
            __bf16 h = (__bf16)hf[c];
            a_h[c] = h;
            a_l[c] = (__bf16)(hf[c] - (float)h);
        }
        #pragma unroll
        for (int nf = 0; nf < 4; ++nf) {
            const size_t bo = (size_t)(nf * 16 + q) * 64 + ks * 32 + sub * 8;
            bf16x8 b_h = *(const bf16x8*)(WrT_h + bo);
            bf16x8 b_l = *(const bf16x8*)(WrT_l + bo);
            acc[nf] = __builtin_amdgcn_mfma_f32_16x16x32_bf16(a_h, b_h, acc[nf], 0, 0, 0);
            acc[nf] = __builtin_amdgcn_mfma_f32_16x16x32_bf16(a_h, b_l, acc[nf], 0, 0, 0);
            acc[nf] = __builtin_amdgcn_mfma_f32_16x16x32_bf16(a_l, b_h, acc[nf], 0, 0, 0);
        }
    }
    // epilogue: + br, relu, store fp32
    #pragma unroll
    for (int nf = 0; nf < 4; ++nf) {
        int col = nf * 16 + q;
        float b = br[col];
        #pragma unroll
        for (int reg = 0; reg < 4; ++reg) {
            int row = rowbase + sub * 4 + reg;
            if (row < n)
                Hout[(size_t)row * 64 + col] = fmaxf(acc[nf][reg] + b, 0.f);
        }
    }
}

extern "C" void kernel_launch(void* const* d_in, const int* in_sizes, int n_in,
                              void* d_out, int out_size, void* d_ws, size_t ws_size,
                              hipStream_t stream) {
    const float* x    = (const float*)d_in[0];
    const int*   ei   = (const int*)d_in[1];
    const float* W1_0 = (const float*)d_in[2];
    const float* W2_0 = (const float*)d_in[3];
    const float* Wr_0 = (const float*)d_in[4];
    const float* br_0 = (const float*)d_in[5];
    const float* W1_1 = (const float*)d_in[6];
    const float* W2_1 = (const float*)d_in[7];
    const float* Wr_1 = (const float*)d_in[8];
    const float* br_1 = (const float*)d_in[9];
    float* out = (float*)d_out;

    const int N = in_sizes[0] / 64;
    const int E = in_sizes[1] / 2;
    const int nchunks = (N + 255) / 256;  // 391 for N=100000 (<= 1024)

    // bump allocator over d_ws (re-poisoned every call -> rebuild everything)
    char* p = (char*)d_ws;
    auto alloc = [&](size_t bytes) { char* r = p; p += (bytes + 255) & ~255ULL; return r; };

    int* deg_in  = (int*)alloc((size_t)N * 4);
    int* deg_out = (int*)alloc((size_t)N * 4);
    int* cur_in  = (int*)alloc((size_t)N * 4);
    int* cur_out = (int*)alloc((size_t)N * 4);
    int* rp_in   = (int*)alloc(((size_t)N + 1) * 4);
    int* rp_out  = (int*)alloc(((size_t)N + 1) * 4);
    int* bsum    = (int*)alloc(2 * 1024 * 4);
    int* ci_in   = (int*)alloc((size_t)E * 4);
    int* ci_out  = (int*)alloc((size_t)E * 4);
    __bf16* Ah   = (__bf16*)alloc((size_t)N * 128 * 2);
    __bf16* Al   = (__bf16*)alloc((size_t)N * 128 * 2);
    float* H     = (float*)alloc((size_t)N * 64 * 4);
    __bf16* WcT_h0 = (__bf16*)alloc(8192 * 2);
    __bf16* WcT_l0 = (__bf16*)alloc(8192 * 2);
    __bf16* WrT_h0 = (__bf16*)alloc(4096 * 2);
    __bf16* WrT_l0 = (__bf16*)alloc(4096 * 2);
    __bf16* WcT_h1 = (__bf16*)alloc(8192 * 2);
    __bf16* WcT_l1 = (__bf16*)alloc(8192 * 2);
    __bf16* WrT_h1 = (__bf16*)alloc(4096 * 2);
    __bf16* WrT_l1 = (__bf16*)alloc(4096 * 2);

    // zero degrees + cursors (contiguous region incl. padding)
    hipMemsetAsync(deg_in, 0, (size_t)((char*)(cur_out + N) - (char*)deg_in), stream);

    int eb = (E + 255) / 256;
    k_degree<<<eb, 256, 0, stream>>>(ei, E, deg_in, deg_out);
    k_chunksum<<<dim3(nchunks, 2), 256, 0, stream>>>(deg_in, deg_out, N, bsum);
    k_scanchunks<<<2, 1024, 0, stream>>>(bsum, nchunks);
    k_scatterscan<<<dim3(nchunks, 2), 256, 0, stream>>>(deg_in, deg_out, N, bsum, rp_in, rp_out);
    k_fill<<<eb, 256, 0, stream>>>(ei, E, rp_in, rp_out, cur_in, cur_out, ci_in, ci_out);

    k_prep<<<48, 256, 0, stream>>>(W1_0, W2_0, Wr_0, WcT_h0, WcT_l0, WrT_h0, WrT_l0);
    k_prep<<<48, 256, 0, stream>>>(W1_1, W2_1, Wr_1, WcT_h1, WcT_l1, WrT_h1, WrT_l1);

    int gb = (N + 3) / 4;           // 4 nodes per 256-thread block
    int mb = (N + 63) / 64;         // 64 rows per GEMM block

    k_gather<<<gb, 256, 0, stream>>>(x, rp_in, ci_in, rp_out, ci_out, Ah, Al, N);
    k_gemm<<<mb, 256, 0, stream>>>(Ah, Al, x, WcT_h0, WcT_l0, WrT_h0, WrT_l0, br_0, H, N);

    k_gather<<<gb, 256, 0, stream>>>(H, rp_in, ci_in, rp_out, ci_out, Ah, Al, N);
    k_gemm<<<mb, 256, 0, stream>>>(Ah, Al, H, WcT_h1, WcT_l1, WrT_h1, WrT_l1, br_1, out, N);
}

// Round 7
// 427.869 us; speedup vs baseline: 1.4296x; 1.4296x over previous
//
#include <hip/hip_runtime.h>

// GNN NodeEncoder: 2 layers of
//   h = relu(x@Wr + br + mean_in(x[src])@W1 + mean_out(x[dst])@W2)
// Algebra: scatter_mean((x@W)[src],dst) == scatter_mean(x[src],dst)@W -> aggregate
// RAW features, apply weights after as a GEMM.
// CSR build is BINNED (512-node buckets) to kill write-allocate amplification
// (round-3 profile: k_fill wrote 163MB HBM for 10MB of ci payload).
// This revision: rp comes from scanning gcnt (bucket totals) + in-kernel LDS
// scan of the per-bucket degree histogram -- the separate degree/scan kernel
// chain (4 kernels + 1.6MB deg traffic) is gone.

typedef __bf16 bf16x8 __attribute__((ext_vector_type(8)));
typedef float  f32x4  __attribute__((ext_vector_type(4)));

#define BSHIFT 9          // 512 nodes per bucket
#define NBMAX  256        // max buckets (N <= 131072, and id must fit 17 bits)
#define CAPLOG 13         // 8192 entries per bucket (mean 6378, sigma ~80 -> +22 sigma)
#define CAP    (1 << CAPLOG)

// ---------------- binned CSR build ----------------
// Pass A: per-block LDS histogram over an 8192-edge chunk, reserve global space
// with one atomic per (block,bucket,dir), then append packed entries:
//   entry = (local_node_id << 17) | neighbor      (N < 2^17, local id < 512)
__launch_bounds__(256)
__global__ void k_bin(const int* __restrict__ ei, int E,
                      int* __restrict__ gcnt /* [2*NBMAX] */,
                      unsigned* __restrict__ binbuf /* [2*NBMAX*CAP] */) {
    __shared__ int lcnt[2 * NBMAX];
    const int tid = threadIdx.x;
    lcnt[tid] = 0; lcnt[NBMAX + tid] = 0;
    __syncthreads();
    const int start = blockIdx.x * 8192;
    const int end = min(start + 8192, E);
    for (int e = start + tid; e < end; e += 256) {
        int s = ei[e], d = ei[E + e];
        atomicAdd(&lcnt[d >> BSHIFT], 1);           // in-dir: bucket by dst
        atomicAdd(&lcnt[NBMAX + (s >> BSHIFT)], 1); // out-dir: bucket by src
    }
    __syncthreads();
    {   // reserve contiguous runs in each bucket; cursor = global base
        int c0 = lcnt[tid], c1 = lcnt[NBMAX + tid];
        int b0 = c0 ? atomicAdd(&gcnt[tid], c0) : 0;
        int b1 = c1 ? atomicAdd(&gcnt[NBMAX + tid], c1) : 0;
        lcnt[tid] = b0; lcnt[NBMAX + tid] = b1;
    }
    __syncthreads();
    for (int e = start + tid; e < end; e += 256) {  // ei re-read is L2-hot
        int s = ei[e], d = ei[E + e];
        int bi = d >> BSHIFT;
        int p = atomicAdd(&lcnt[bi], 1);
        if (p < CAP)
            binbuf[(bi << CAPLOG) + p] = ((unsigned)(d & 511) << 17) | (unsigned)s;
        int bo = s >> BSHIFT;
        int p2 = atomicAdd(&lcnt[NBMAX + bo], 1);
        if (p2 < CAP)
            binbuf[((NBMAX + bo) << CAPLOG) + p2] = ((unsigned)(s & 511) << 17) | (unsigned)d;
    }
}

// Exclusive scan of bucket totals -> bucket base offsets. gcnt[bkt] IS the sum
// of degrees in bucket bkt, so this replaces the whole node-degree scan chain.
// blockIdx.x = dir; 256 threads scan NBMAX=256 entries (unused buckets are 0).
__launch_bounds__(256)
__global__ void k_scanbase(const int* __restrict__ gcnt, int* __restrict__ gbase) {
    __shared__ int sm[NBMAX];
    const int tid = threadIdx.x;
    int v = gcnt[blockIdx.x * NBMAX + tid];
    sm[tid] = v;
    __syncthreads();
    for (int off = 1; off < NBMAX; off <<= 1) {
        int t = (tid >= off) ? sm[tid - off] : 0;
        __syncthreads();
        sm[tid] += t;
        __syncthreads();
    }
    gbase[blockIdx.x * NBMAX + tid] = sm[tid] - v;  // exclusive
}

// Pass B: per (bucket,dir) block. LDS degree histogram -> Blelloch exclusive
// scan (512 elems, 256 threads) -> write rp (contiguous) + scatter ci via LDS
// cursors. Each bucket's ci region (~25KB) is written by ONE block.
__launch_bounds__(256)
__global__ void k_binfill2(const unsigned* __restrict__ binbuf, const int* __restrict__ gcnt,
                           const int* __restrict__ gbase, int n,
                           int* __restrict__ rp_in, int* __restrict__ rp_out,
                           int* __restrict__ ci_in, int* __restrict__ ci_out) {
    __shared__ int h[512];     // histogram -> exclusive scan
    __shared__ int cur[512];   // scatter cursors
    __shared__ int s_tot;
    const int dir = blockIdx.y, bkt = blockIdx.x, tid = threadIdx.x;
    int* rp = dir ? rp_out : rp_in;
    int* ci = dir ? ci_out : ci_in;
    h[tid] = 0; h[256 + tid] = 0;
    __syncthreads();
    const int cnt = min(gcnt[dir * NBMAX + bkt], CAP);
    const unsigned* buf = binbuf + (((size_t)dir * NBMAX + bkt) << CAPLOG);
    for (int i = tid; i < cnt; i += 256)
        atomicAdd(&h[buf[i] >> 17], 1);
    __syncthreads();
    // Blelloch up-sweep
    for (int d = 1; d < 512; d <<= 1) {
        int idx = (tid + 1) * (d << 1) - 1;
        if (idx < 512) h[idx] += h[idx - d];
        __syncthreads();
    }
    if (tid == 0) { s_tot = h[511]; h[511] = 0; }
    __syncthreads();
    // down-sweep -> exclusive scan
    for (int d = 256; d >= 1; d >>= 1) {
        int idx = (tid + 1) * (d << 1) - 1;
        if (idx < 512) { int t = h[idx - d]; h[idx - d] = h[idx]; h[idx] += t; }
        __syncthreads();
    }
    const int base_off = gbase[dir * NBMAX + bkt];
    const int nodebase = bkt << BSHIFT;
    for (int i = tid; i < 512; i += 256) {
        int nd = nodebase + i;
        int v = base_off + h[i];
        cur[i] = v;
        if (nd < n) rp[nd] = v;
    }
    if (tid == 0 && ((n - 1) >> BSHIFT) == bkt)
        rp[n] = base_off + s_tot;           // final row pointer
    __syncthreads();
    for (int i = tid; i < cnt; i += 256) {  // buf re-read is L2-hot (~25KB)
        unsigned ent = buf[i];
        int slot = atomicAdd(&cur[ent >> 17], 1);
        ci[slot] = (int)(ent & 0x1FFFFu);
    }
}

// ---------------- weight prep: WcatT = [W1;W2]^T, WrT = Wr^T, split bf16 ----------------
__global__ void k_prep(const float* __restrict__ W1, const float* __restrict__ W2,
                       const float* __restrict__ Wr,
                       __bf16* __restrict__ WcT_h, __bf16* __restrict__ WcT_l,
                       __bf16* __restrict__ WrT_h, __bf16* __restrict__ WrT_l) {
    int i = blockIdx.x * 256 + threadIdx.x;  // 12288 total
    if (i < 8192) {
        int nn = i >> 7, k = i & 127;
        float w = (k < 64) ? W1[k * 64 + nn] : W2[(k - 64) * 64 + nn];
        __bf16 h = (__bf16)w;
        WcT_h[i] = h;
        WcT_l[i] = (__bf16)(w - (float)h);
    } else if (i < 12288) {
        int j = i - 8192;
        int nn = j >> 6, k = j & 63;
        float w = Wr[k * 64 + nn];
        __bf16 h = (__bf16)w;
        WrT_h[j] = h;
        WrT_l[j] = (__bf16)(w - (float)h);
    }
}

// ---------------- gather: per-node wave, float4 rows, split-bf16 A out ----------------
__launch_bounds__(256, 8)
__global__ void k_gather(const float* __restrict__ Hin,
                         const int* __restrict__ rp_in, const int* __restrict__ ci_in,
                         const int* __restrict__ rp_out, const int* __restrict__ ci_out,
                         __bf16* __restrict__ Ah, __bf16* __restrict__ Al, int n) {
    const int lane = threadIdx.x & 63;
    const int wid  = threadIdx.x >> 6;
    const int v = blockIdx.x * 4 + wid;
    if (v >= n) return;
    const int q = lane & 15, sub = lane >> 4;

    #pragma unroll
    for (int dir = 0; dir < 2; ++dir) {
        const int* rp = dir ? rp_out : rp_in;
        const int* ci = dir ? ci_out : ci_in;
        int s = rp[v], e = rp[v + 1];
        float ax = 0.f, ay = 0.f, az = 0.f, aw = 0.f;
        int t = s;
        for (; t + 8 <= e; t += 8) {  // 8 rows per iter, 2 x 1KB gathers in flight
            int u0 = ci[t + sub];
            int u1 = ci[t + 4 + sub];
            float4 f0 = *(const float4*)(Hin + (size_t)u0 * 64 + q * 4);
            float4 f1 = *(const float4*)(Hin + (size_t)u1 * 64 + q * 4);
            ax += f0.x + f1.x; ay += f0.y + f1.y;
            az += f0.z + f1.z; aw += f0.w + f1.w;
        }
        for (; t < e; t += 4) {  // tail, predicated per sub-group
            int r = t + sub;
            if (r < e) {
                int u = ci[r];
                float4 f = *(const float4*)(Hin + (size_t)u * 64 + q * 4);
                ax += f.x; ay += f.y; az += f.z; aw += f.w;
            }
        }
        ax += __shfl_xor(ax, 16, 64); ax += __shfl_xor(ax, 32, 64);
        ay += __shfl_xor(ay, 16, 64); ay += __shfl_xor(ay, 32, 64);
        az += __shfl_xor(az, 16, 64); az += __shfl_xor(az, 32, 64);
        aw += __shfl_xor(aw, 16, 64); aw += __shfl_xor(aw, 32, 64);
        float inv = 1.0f / (float)max(e - s, 1);
        ax *= inv; ay *= inv; az *= inv; aw *= inv;

        if (sub == 0) {
            union { __bf16 h[4]; uint2 u2; } ph, pl;
            float m[4] = {ax, ay, az, aw};
            #pragma unroll
            for (int c = 0; c < 4; ++c) {
                __bf16 h = (__bf16)m[c];
                ph.h[c] = h;
                pl.h[c] = (__bf16)(m[c] - (float)h);
            }
            size_t off = (size_t)v * 128 + dir * 64 + q * 4;
            *(uint2*)(Ah + off) = ph.u2;
            *(uint2*)(Al + off) = pl.u2;
        }
    }
}

// ---------------- MFMA GEMM: out = relu(A@Wcat + Hin@Wr + br) ----------------
// mfma_f32_16x16x32_bf16; identical k-packing for A and B makes the internal
// k-order cancel. C/D: col = lane&15, row = (lane>>4)*4 + reg  [verified m89]
__global__ void k_gemm(const __bf16* __restrict__ Ah, const __bf16* __restrict__ Al,
                       const float* __restrict__ Hin,
                       const __bf16* __restrict__ WcT_h, const __bf16* __restrict__ WcT_l,
                       const __bf16* __restrict__ WrT_h, const __bf16* __restrict__ WrT_l,
                       const float* __restrict__ br, float* __restrict__ Hout, int n) {
    const int lane = threadIdx.x & 63;
    const int wid  = threadIdx.x >> 6;
    const int q = lane & 15, sub = lane >> 4;
    const int rowbase = blockIdx.x * 64 + wid * 16;
    const int arow = min(rowbase + q, n - 1);

    f32x4 acc[4];
    #pragma unroll
    for (int nf = 0; nf < 4; ++nf) acc[nf] = (f32x4){0.f, 0.f, 0.f, 0.f};

    // A @ Wcat  (K = 128)
    #pragma unroll
    for (int ks = 0; ks < 4; ++ks) {
        const size_t ao = (size_t)arow * 128 + ks * 32 + sub * 8;
        bf16x8 a_h = *(const bf16x8*)(Ah + ao);
        bf16x8 a_l = *(const bf16x8*)(Al + ao);
        #pragma unroll
        for (int nf = 0; nf < 4; ++nf) {
            const size_t bo = (size_t)(nf * 16 + q) * 128 + ks * 32 + sub * 8;
            bf16x8 b_h = *(const bf16x8*)(WcT_h + bo);
            bf16x8 b_l = *(const bf16x8*)(WcT_l + bo);
            acc[nf] = __builtin_amdgcn_mfma_f32_16x16x32_bf16(a_h, b_h, acc[nf], 0, 0, 0);
            acc[nf] = __builtin_amdgcn_mfma_f32_16x16x32_bf16(a_h, b_l, acc[nf], 0, 0, 0);
            acc[nf] = __builtin_amdgcn_mfma_f32_16x16x32_bf16(a_l, b_h, acc[nf], 0, 0, 0);
        }
    }
    // Hin @ Wr  (K = 64), fp32 -> hi/lo split in-register
    #pragma unroll
    for (int ks = 0; ks < 2; ++ks) {
        const float* hp = Hin + (size_t)arow * 64 + ks * 32 + sub * 8;
        float4 h0 = *(const float4*)hp;
        float4 h1 = *(const float4*)(hp + 4);
        float hf[8] = {h0.x, h0.y, h0.z, h0.w, h1.x, h1.y, h1.z, h1.w};
        bf16x8 a_h, a_l;
        #pragma unroll
        for (int c = 0; c < 8; ++c) {
            __bf16 h = (__bf16)hf[c];
            a_h[c] = h;
            a_l[c] = (__bf16)(hf[c] - (float)h);
        }
        #pragma unroll
        for (int nf = 0; nf < 4; ++nf) {
            const size_t bo = (size_t)(nf * 16 + q) * 64 + ks * 32 + sub * 8;
            bf16x8 b_h = *(const bf16x8*)(WrT_h + bo);
            bf16x8 b_l = *(const bf16x8*)(WrT_l + bo);
            acc[nf] = __builtin_amdgcn_mfma_f32_16x16x32_bf16(a_h, b_h, acc[nf], 0, 0, 0);
            acc[nf] = __builtin_amdgcn_mfma_f32_16x16x32_bf16(a_h, b_l, acc[nf], 0, 0, 0);
            acc[nf] = __builtin_amdgcn_mfma_f32_16x16x32_bf16(a_l, b_h, acc[nf], 0, 0, 0);
        }
    }
    #pragma unroll
    for (int nf = 0; nf < 4; ++nf) {
        int col = nf * 16 + q;
        float b = br[col];
        #pragma unroll
        for (int reg = 0; reg < 4; ++reg) {
            int row = rowbase + sub * 4 + reg;
            if (row < n)
                Hout[(size_t)row * 64 + col] = fmaxf(acc[nf][reg] + b, 0.f);
        }
    }
}

extern "C" void kernel_launch(void* const* d_in, const int* in_sizes, int n_in,
                              void* d_out, int out_size, void* d_ws, size_t ws_size,
                              hipStream_t stream) {
    const float* x    = (const float*)d_in[0];
    const int*   ei   = (const int*)d_in[1];
    const float* W1_0 = (const float*)d_in[2];
    const float* W2_0 = (const float*)d_in[3];
    const float* Wr_0 = (const float*)d_in[4];
    const float* br_0 = (const float*)d_in[5];
    const float* W1_1 = (const float*)d_in[6];
    const float* W2_1 = (const float*)d_in[7];
    const float* Wr_1 = (const float*)d_in[8];
    const float* br_1 = (const float*)d_in[9];
    float* out = (float*)d_out;

    const int N = in_sizes[0] / 64;
    const int E = in_sizes[1] / 2;
    const int NB = (N + 511) >> BSHIFT;       // 196 buckets (<= NBMAX)

    // bump allocator over d_ws (re-poisoned every call -> rebuild everything)
    char* p = (char*)d_ws;
    auto alloc = [&](size_t bytes) { char* r = p; p += (bytes + 255) & ~255ULL; return r; };

    int* rp_in   = (int*)alloc(((size_t)N + 1) * 4);
    int* rp_out  = (int*)alloc(((size_t)N + 1) * 4);
    int* gcnt    = (int*)alloc(2 * NBMAX * 4);
    int* gbase   = (int*)alloc(2 * NBMAX * 4);
    int* ci_in   = (int*)alloc((size_t)E * 4);
    int* ci_out  = (int*)alloc((size_t)E * 4);
    __bf16* Ah   = (__bf16*)alloc((size_t)N * 128 * 2);
    __bf16* Al   = (__bf16*)alloc((size_t)N * 128 * 2);
    float* H     = (float*)alloc((size_t)N * 64 * 4);
    __bf16* WcT_h0 = (__bf16*)alloc(8192 * 2);
    __bf16* WcT_l0 = (__bf16*)alloc(8192 * 2);
    __bf16* WrT_h0 = (__bf16*)alloc(4096 * 2);
    __bf16* WrT_l0 = (__bf16*)alloc(4096 * 2);
    __bf16* WcT_h1 = (__bf16*)alloc(8192 * 2);
    __bf16* WcT_l1 = (__bf16*)alloc(8192 * 2);
    __bf16* WrT_h1 = (__bf16*)alloc(4096 * 2);
    __bf16* WrT_l1 = (__bf16*)alloc(4096 * 2);

    // binbuf (2*NBMAX*CAP*4B = 16.8MB) aliases Ah/Al: dead before first k_gather.
    unsigned* binbuf = (unsigned*)Ah;

    hipMemsetAsync(gcnt, 0, 2 * NBMAX * 4, stream);

    int bb = (E + 8191) / 8192;
    k_bin<<<bb, 256, 0, stream>>>(ei, E, gcnt, binbuf);
    k_scanbase<<<2, NBMAX, 0, stream>>>(gcnt, gbase);
    k_binfill2<<<dim3(NB, 2), 256, 0, stream>>>(binbuf, gcnt, gbase, N,
                                                rp_in, rp_out, ci_in, ci_out);

    k_prep<<<48, 256, 0, stream>>>(W1_0, W2_0, Wr_0, WcT_h0, WcT_l0, WrT_h0, WrT_l0);
    k_prep<<<48, 256, 0, stream>>>(W1_1, W2_1, Wr_1, WcT_h1, WcT_l1, WrT_h1, WrT_l1);

    int gb = (N + 3) / 4;           // 4 nodes per 256-thread block
    int mb = (N + 63) / 64;         // 64 rows per GEMM block

    k_gather<<<gb, 256, 0, stream>>>(x, rp_in, ci_in, rp_out, ci_out, Ah, Al, N);
    k_gemm<<<mb, 256, 0, stream>>>(Ah, Al, x, WcT_h0, WcT_l0, WrT_h0, WrT_l0, br_0, H, N);

    k_gather<<<gb, 256, 0, stream>>>(H, rp_in, ci_in, rp_out, ci_out, Ah, Al, N);
    k_gemm<<<mb, 256, 0, stream>>>(Ah, Al, H, WcT_h1, WcT_l1, WrT_h1, WrT_l1, br_1, out, N);
}